// Round 9
// baseline (970.497 us; speedup 1.0000x reference)
//
#include <hip/hip_runtime.h>
#include <hip/hip_bf16.h>
#include <stdint.h>

// Net_61272003445332: GraphSAGE w/ LSTM aggregator, N=20000, K=16,
// dims: l0 (din=64,dout=128), l1 (128,128), l2 (128,32).
// R8 = R7 with amdgpu_waves_per_eu(4) -> (8). R7 counters: VGPR=64 (exactly
// the 8-wave/SIMD budget), Occupancy 37%, VALUBusy 63% -> occupancy still the
// binding constraint; 4 blocks/CU overlap barrier/trans/gather latency.

#define N_NODES 20000
#define KNE 16

typedef __bf16 bf16x8 __attribute__((ext_vector_type(8)));
typedef float f32x4 __attribute__((ext_vector_type(4)));

__device__ __forceinline__ bf16x8 ldb8(const __hip_bfloat16* p) {
  uint4 u = *reinterpret_cast<const uint4*>(p);
  return __builtin_bit_cast(bf16x8, u);
}
// Anti-rematerialization pin: each 32-bit word passes through a no-op asm
// (scalar "+v" ties are supported; 128-bit ties are not).
__device__ __forceinline__ void pin(bf16x8& v) {
  uint4 u = __builtin_bit_cast(uint4, v);
  asm volatile("" : "+v"(u.x), "+v"(u.y), "+v"(u.z), "+v"(u.w));
  v = __builtin_bit_cast(bf16x8, u);
}
__device__ __forceinline__ float b2f_lo(uint32_t u) {
  return __builtin_bit_cast(float, u << 16);
}
__device__ __forceinline__ float b2f_hi(uint32_t u) {
  return __builtin_bit_cast(float, u & 0xffff0000u);
}
// NaN-safe, clamp-free saturating forms.
__device__ __forceinline__ float sigf(float x) {
  float t = __builtin_amdgcn_exp2f(-1.442695041f * x);
  return __builtin_amdgcn_rcpf(1.f + t);
}
__device__ __forceinline__ float tanhf_(float x) {
  float t = __builtin_amdgcn_exp2f(2.885390082f * x);
  return 1.f - 2.f * __builtin_amdgcn_rcpf(t + 1.f);
}

__global__ void build_feat0(const float* __restrict__ p,
                            __hip_bfloat16* __restrict__ f0) {
  int i = blockIdx.x * 256 + threadIdx.x;
  if (i >= N_NODES * 64) return;
  int n = i >> 6, c = i & 63;
  float v = (c == 0) ? ((float)KNE / (float)N_NODES) : p[n * 63 + c - 1];
  f0[i] = __float2bfloat16(v);
}

__global__ void cvt4(const float* __restrict__ s0, int n0,
                     const float* __restrict__ s1, int n1,
                     const float* __restrict__ s2, int n2,
                     const float* __restrict__ s3, int n3,
                     __hip_bfloat16* __restrict__ d0,
                     __hip_bfloat16* __restrict__ d1,
                     __hip_bfloat16* __restrict__ d2,
                     __hip_bfloat16* __restrict__ d3) {
  int i = blockIdx.x * 256 + threadIdx.x;
  if (i < n0) { d0[i] = __float2bfloat16(s0[i]); return; }
  i -= n0;
  if (i < n1) { d1[i] = __float2bfloat16(s1[i]); return; }
  i -= n1;
  if (i < n2) { d2[i] = __float2bfloat16(s2[i]); return; }
  i -= n2;
  if (i < n3) d3[i] = __float2bfloat16(s3[i]);
}

// P = feat@Wih.T + (bih+bhh) -> bf16 GATE-PACKED: P[n][cc*4+g], cc=col%DIN
// S = feat@Wself.T + b       -> f32 [N,DOUT]
template <int DIN, int DOUT>
__global__ __launch_bounds__(256, 2) void proj_kern(
    const __hip_bfloat16* __restrict__ feat,
    const __hip_bfloat16* __restrict__ Wih,   // bf16 [4*DIN, DIN]
    const float* __restrict__ bih,
    const float* __restrict__ bhh,
    const __hip_bfloat16* __restrict__ Wself, // bf16 [DOUT, DIN]
    const float* __restrict__ bvec,
    __hip_bfloat16* __restrict__ P, float* __restrict__ S) {
  constexpr int KB = DIN / 32;
  constexpr int CTP = 4 * DIN / 16;
  constexpr int CTS = DOUT / 16;
  const int n0 = blockIdx.x * 32;
  const int tid = threadIdx.x;
  const int wv = tid >> 6;
  const int lane = tid & 63;
  const int quad = lane >> 4;
  const int c16 = lane & 15;

  bf16x8 afr[2][KB];
#pragma unroll
  for (int rt = 0; rt < 2; ++rt)
#pragma unroll
    for (int kb = 0; kb < KB; ++kb)
      afr[rt][kb] =
          ldb8(feat + (size_t)(n0 + rt * 16 + c16) * DIN + kb * 32 + quad * 8);

  const f32x4 zz = {0.f, 0.f, 0.f, 0.f};
  for (int ct = wv; ct < CTP + CTS; ct += 4) {
    f32x4 a0 = zz, a1 = zz;
    const __hip_bfloat16* W;
    int row;
    if (ct < CTP) { W = Wih; row = ct * 16 + c16; }
    else          { W = Wself; row = (ct - CTP) * 16 + c16; }
#pragma unroll
    for (int kb = 0; kb < KB; ++kb) {
      bf16x8 b = ldb8(W + (size_t)row * DIN + kb * 32 + quad * 8);
      a0 = __builtin_amdgcn_mfma_f32_16x16x32_bf16(afr[0][kb], b, a0, 0, 0, 0);
      a1 = __builtin_amdgcn_mfma_f32_16x16x32_bf16(afr[1][kb], b, a1, 0, 0, 0);
    }
    if (ct < CTP) {
      int c = ct * 16 + c16;
      int gg = c / DIN, cc = c % DIN;
      float bias = bih[c] + bhh[c];
#pragma unroll
      for (int r = 0; r < 4; ++r) {
        P[(size_t)(n0 + quad * 4 + r) * (4 * DIN) + cc * 4 + gg] =
            __float2bfloat16(a0[r] + bias);
        P[(size_t)(n0 + 16 + quad * 4 + r) * (4 * DIN) + cc * 4 + gg] =
            __float2bfloat16(a1[r] + bias);
      }
    } else {
      int c = (ct - CTP) * 16 + c16;
      float bias = bvec[c];
#pragma unroll
      for (int r = 0; r < 4; ++r) {
        S[(size_t)(n0 + quad * 4 + r) * DOUT + c] = a0[r] + bias;
        S[(size_t)(n0 + 16 + quad * 4 + r) * DOUT + c] = a1[r] + bias;
      }
    }
  }
}

// LSTM + fused fc. Block = (DIN/16) waves = 16 nodes.
// Wave wv owns cols [wv*16, wv*16+16) of ALL 4 gates; Whh frags pinned in
// VGPRs (4*KB bf16x8). pf gathers double-buffered; t-loop fully unrolled.
template <int DIN, int DOUT, bool RELU, typename OutT>
__global__ __launch_bounds__((DIN / 16) * 64)
__attribute__((amdgpu_waves_per_eu(8))) void lstm_fc_kern(
    const __hip_bfloat16* __restrict__ P,   // [N][DIN][4] gate-packed bf16
    const float* __restrict__ S,            // [N, DOUT] f32
    const __hip_bfloat16* __restrict__ Whh, // bf16 [4*DIN, DIN]
    const __hip_bfloat16* __restrict__ Wng, // bf16 [DOUT, DIN]
    const int* __restrict__ nidx,           // [N, 16]
    OutT* __restrict__ outp) {              // [N, DOUT]
  constexpr int W = DIN / 16;    // waves per block
  constexpr int KB = DIN / 32;   // MFMA K blocks
  constexpr int HS = DIN + 8;    // h row stride

  __shared__ __align__(16) __hip_bfloat16 hl[2][16 * HS];
  __shared__ int idxl[16 * KNE];

  const int n0 = blockIdx.x * 16;
  const int tid = threadIdx.x;
  const int wv = tid >> 6;
  const int lane = tid & 63;
  const int quad = lane >> 4;
  const int c16 = lane & 15;
  const int col = wv * 16 + c16;  // this lane's h/gate column

  for (int i = tid; i < 16 * KNE; i += W * 64) idxl[i] = nidx[n0 * KNE + i];
  __syncthreads();  // idxl ready

  uint2 pf[2][4];
  auto loadpf = [&](int t, int b) {
#pragma unroll
    for (int r = 0; r < 4; ++r) {
      int src = idxl[(quad * 4 + r) * KNE + t];
      pf[b][r] =
          reinterpret_cast<const uint2*>(P + (size_t)src * (4 * DIN))[col];
    }
  };

  loadpf(0, 0);  // needed immediately at t=0

  // Persistent Whh B-fragments: rows g*DIN + col. Pinned against remat.
  bf16x8 Bp[4][KB];
#pragma unroll
  for (int g = 0; g < 4; ++g)
#pragma unroll
    for (int kb = 0; kb < KB; ++kb) {
      Bp[g][kb] =
          ldb8(Whh + (size_t)(g * DIN + col) * DIN + kb * 32 + quad * 8);
      pin(Bp[g][kb]);
    }

  loadpf(1, 1);  // prefetch step 1

  float cst[4];
#pragma unroll
  for (int r = 0; r < 4; ++r) cst[r] = 0.f;

  // gates: element (node m = quad*4+r, col); pf buffer b; h buffer hb.
  auto gates = [&](int hb, int b, const f32x4 (&ag)[4]) {
#pragma unroll
    for (int r = 0; r < 4; ++r) {
      float vi = ag[0][r] + b2f_lo(pf[b][r].x);
      float vf = ag[1][r] + b2f_hi(pf[b][r].x);
      float vg = ag[2][r] + b2f_lo(pf[b][r].y);
      float vo = ag[3][r] + b2f_hi(pf[b][r].y);
      float cc = sigf(vf) * cst[r] + sigf(vi) * tanhf_(vg);
      cst[r] = cc;
      hl[hb][(quad * 4 + r) * HS + col] =
          __float2bfloat16(sigf(vo) * tanhf_(cc));
    }
  };

  const f32x4 zz = {0.f, 0.f, 0.f, 0.f};

  // t = 0: h == 0.
  {
    f32x4 ag[4] = {zz, zz, zz, zz};
    gates(0, 0, ag);
  }

#pragma unroll
  for (int t = 1; t < KNE; ++t) {  // FULL unroll: all pf/hl indices static
    __syncthreads();  // h(t-1) visible
    if (t + 1 < KNE) loadpf(t + 1, (t + 1) & 1);
    const int pb = (t - 1) & 1;
    bf16x8 Af[KB];
#pragma unroll
    for (int kb = 0; kb < KB; ++kb)
      Af[kb] = ldb8(&hl[pb][c16 * HS + kb * 32 + quad * 8]);
    f32x4 ag[4] = {zz, zz, zz, zz};
#pragma unroll
    for (int kb = 0; kb < KB; ++kb)
#pragma unroll
      for (int g = 0; g < 4; ++g)
        ag[g] = __builtin_amdgcn_mfma_f32_16x16x32_bf16(Af[kb], Bp[g][kb],
                                                        ag[g], 0, 0, 0);
    gates(t & 1, t & 1, ag);
  }

  __syncthreads();  // final h (hl[1], 15&1==1) visible
  bf16x8 Hf[KB];
#pragma unroll
  for (int kb = 0; kb < KB; ++kb)
    Hf[kb] = ldb8(&hl[1][c16 * HS + kb * 32 + quad * 8]);
  for (int ct = wv; ct < DOUT / 16; ct += W) {
    f32x4 a = zz;
#pragma unroll
    for (int kb = 0; kb < KB; ++kb) {
      bf16x8 b = ldb8(Wng + (size_t)(ct * 16 + c16) * DIN + kb * 32 + quad * 8);
      a = __builtin_amdgcn_mfma_f32_16x16x32_bf16(Hf[kb], b, a, 0, 0, 0);
    }
#pragma unroll
    for (int r = 0; r < 4; ++r) {
      int n = n0 + quad * 4 + r;
      int c = ct * 16 + c16;
      float v = a[r] + S[(size_t)n * DOUT + c];
      if (RELU) v = fmaxf(v, 0.f);
      if constexpr (sizeof(OutT) == 2)
        outp[(size_t)n * DOUT + c] = __float2bfloat16(v);
      else
        outp[(size_t)n * DOUT + c] = v;
    }
  }
}

extern "C" void kernel_launch(void* const* d_in, const int* in_sizes, int n_in,
                              void* d_out, int out_size, void* d_ws,
                              size_t ws_size, hipStream_t stream) {
  (void)in_sizes; (void)n_in; (void)out_size; (void)ws_size;
  const float* p = (const float*)d_in[0];
  const int* nidx = (const int*)d_in[1];
  const float* L[3][7];
  for (int l = 0; l < 3; ++l)
    for (int j = 0; j < 7; ++j)
      L[l][j] = (const float*)d_in[2 + 7 * l + j];
  // per-layer params: 0=Wih 1=Whh 2=bih 3=bhh 4=Wself 5=Wneigh 6=b

  char* w = (char*)d_ws;
  __hip_bfloat16* feat0 = (__hip_bfloat16*)(w);             // N*64*2  = 2.56MB
  __hip_bfloat16* feat1 = (__hip_bfloat16*)(w + 2560000);   // N*128*2 = 5.12MB
  __hip_bfloat16* feat2 = (__hip_bfloat16*)(w + 7680000);   // N*128*2 = 5.12MB
  __hip_bfloat16* Pb    = (__hip_bfloat16*)(w + 12800000);  // N*512*2 = 20.48MB
  float*          Sb    = (float*)(w + 33280000);           // N*128*4 = 10.24MB
  __hip_bfloat16* wb    = (__hip_bfloat16*)(w + 43520000);  // bf16 weights

  const int din_[3] = {64, 128, 128}, dout_[3] = {128, 128, 32};
  __hip_bfloat16 *Wih_b[3], *Whh_b[3], *Wself_b[3], *Wng_b[3];
  size_t off = 0;
  for (int l = 0; l < 3; ++l) {
    int din = din_[l], dout = dout_[l];
    Wih_b[l] = wb + off;   off += (size_t)4 * din * din;
    Whh_b[l] = wb + off;   off += (size_t)4 * din * din;
    Wself_b[l] = wb + off; off += (size_t)dout * din;
    Wng_b[l] = wb + off;   off += (size_t)dout * din;
  }
  for (int l = 0; l < 3; ++l) {
    int din = din_[l], dout = dout_[l];
    int n0 = 4 * din * din, n2 = dout * din;
    int tot = 2 * n0 + 2 * n2;
    cvt4<<<(tot + 255) / 256, 256, 0, stream>>>(
        L[l][0], n0, L[l][1], n0, L[l][4], n2, L[l][5], n2,
        Wih_b[l], Whh_b[l], Wself_b[l], Wng_b[l]);
  }

  build_feat0<<<(N_NODES * 64 + 255) / 256, 256, 0, stream>>>(p, feat0);

  // layer 0: din=64, dout=128  (lstm block = 4 waves)
  proj_kern<64, 128><<<N_NODES / 32, 256, 0, stream>>>(
      feat0, Wih_b[0], L[0][2], L[0][3], Wself_b[0], L[0][6], Pb, Sb);
  lstm_fc_kern<64, 128, true, __hip_bfloat16>
      <<<N_NODES / 16, 256, 0, stream>>>(Pb, Sb, Whh_b[0], Wng_b[0], nidx,
                                         feat1);

  // layer 1: din=128, dout=128  (lstm block = 8 waves)
  proj_kern<128, 128><<<N_NODES / 32, 256, 0, stream>>>(
      feat1, Wih_b[1], L[1][2], L[1][3], Wself_b[1], L[1][6], Pb, Sb);
  lstm_fc_kern<128, 128, true, __hip_bfloat16>
      <<<N_NODES / 16, 512, 0, stream>>>(Pb, Sb, Whh_b[1], Wng_b[1], nidx,
                                         feat2);

  // layer 2: din=128, dout=32 (no relu; final fp32 output)
  proj_kern<128, 32><<<N_NODES / 32, 256, 0, stream>>>(
      feat2, Wih_b[2], L[2][2], L[2][3], Wself_b[2], L[2][6], Pb, Sb);
  lstm_fc_kern<128, 32, false, float>
      <<<N_NODES / 16, 512, 0, stream>>>(Pb, Sb, Whh_b[2], Wng_b[2], nidx,
                                         (float*)d_out);
}

// Round 10
// 741.894 us; speedup vs baseline: 1.3081x; 1.3081x over previous
//
#include <hip/hip_runtime.h>
#include <hip/hip_bf16.h>
#include <stdint.h>

// Net_61272003445332: GraphSAGE w/ LSTM aggregator, N=20000, K=16,
// dims: l0 (din=64,dout=128), l1 (128,128), l2 (128,32).
// R9 = R7 with (a) amdgpu_waves_per_eu(6): budget ~80 VGPR >= the kernel's
// proven 64-VGPR fit -> no spill (R8's (8) squeezed below 64 and thrashed
// scratch: WRITE 355MB, VGPR 32), residency setpoint 6 waves/SIMD; and
// (b) gate pre-acts folded into the MFMA accumulator init (C=pf, not 0)
// -> 16 fewer v_add per lane-step.

#define N_NODES 20000
#define KNE 16

typedef __bf16 bf16x8 __attribute__((ext_vector_type(8)));
typedef float f32x4 __attribute__((ext_vector_type(4)));

__device__ __forceinline__ bf16x8 ldb8(const __hip_bfloat16* p) {
  uint4 u = *reinterpret_cast<const uint4*>(p);
  return __builtin_bit_cast(bf16x8, u);
}
// Anti-rematerialization pin: each 32-bit word passes through a no-op asm
// (scalar "+v" ties are supported; 128-bit ties are not).
__device__ __forceinline__ void pin(bf16x8& v) {
  uint4 u = __builtin_bit_cast(uint4, v);
  asm volatile("" : "+v"(u.x), "+v"(u.y), "+v"(u.z), "+v"(u.w));
  v = __builtin_bit_cast(bf16x8, u);
}
__device__ __forceinline__ float b2f_lo(uint32_t u) {
  return __builtin_bit_cast(float, u << 16);
}
__device__ __forceinline__ float b2f_hi(uint32_t u) {
  return __builtin_bit_cast(float, u & 0xffff0000u);
}
// NaN-safe, clamp-free saturating forms.
__device__ __forceinline__ float sigf(float x) {
  float t = __builtin_amdgcn_exp2f(-1.442695041f * x);
  return __builtin_amdgcn_rcpf(1.f + t);
}
__device__ __forceinline__ float tanhf_(float x) {
  float t = __builtin_amdgcn_exp2f(2.885390082f * x);
  return 1.f - 2.f * __builtin_amdgcn_rcpf(t + 1.f);
}

__global__ void build_feat0(const float* __restrict__ p,
                            __hip_bfloat16* __restrict__ f0) {
  int i = blockIdx.x * 256 + threadIdx.x;
  if (i >= N_NODES * 64) return;
  int n = i >> 6, c = i & 63;
  float v = (c == 0) ? ((float)KNE / (float)N_NODES) : p[n * 63 + c - 1];
  f0[i] = __float2bfloat16(v);
}

__global__ void cvt4(const float* __restrict__ s0, int n0,
                     const float* __restrict__ s1, int n1,
                     const float* __restrict__ s2, int n2,
                     const float* __restrict__ s3, int n3,
                     __hip_bfloat16* __restrict__ d0,
                     __hip_bfloat16* __restrict__ d1,
                     __hip_bfloat16* __restrict__ d2,
                     __hip_bfloat16* __restrict__ d3) {
  int i = blockIdx.x * 256 + threadIdx.x;
  if (i < n0) { d0[i] = __float2bfloat16(s0[i]); return; }
  i -= n0;
  if (i < n1) { d1[i] = __float2bfloat16(s1[i]); return; }
  i -= n1;
  if (i < n2) { d2[i] = __float2bfloat16(s2[i]); return; }
  i -= n2;
  if (i < n3) d3[i] = __float2bfloat16(s3[i]);
}

// P = feat@Wih.T + (bih+bhh) -> bf16 GATE-PACKED: P[n][cc*4+g], cc=col%DIN
// S = feat@Wself.T + b       -> f32 [N,DOUT]
template <int DIN, int DOUT>
__global__ __launch_bounds__(256, 2) void proj_kern(
    const __hip_bfloat16* __restrict__ feat,
    const __hip_bfloat16* __restrict__ Wih,   // bf16 [4*DIN, DIN]
    const float* __restrict__ bih,
    const float* __restrict__ bhh,
    const __hip_bfloat16* __restrict__ Wself, // bf16 [DOUT, DIN]
    const float* __restrict__ bvec,
    __hip_bfloat16* __restrict__ P, float* __restrict__ S) {
  constexpr int KB = DIN / 32;
  constexpr int CTP = 4 * DIN / 16;
  constexpr int CTS = DOUT / 16;
  const int n0 = blockIdx.x * 32;
  const int tid = threadIdx.x;
  const int wv = tid >> 6;
  const int lane = tid & 63;
  const int quad = lane >> 4;
  const int c16 = lane & 15;

  bf16x8 afr[2][KB];
#pragma unroll
  for (int rt = 0; rt < 2; ++rt)
#pragma unroll
    for (int kb = 0; kb < KB; ++kb)
      afr[rt][kb] =
          ldb8(feat + (size_t)(n0 + rt * 16 + c16) * DIN + kb * 32 + quad * 8);

  const f32x4 zz = {0.f, 0.f, 0.f, 0.f};
  for (int ct = wv; ct < CTP + CTS; ct += 4) {
    f32x4 a0 = zz, a1 = zz;
    const __hip_bfloat16* W;
    int row;
    if (ct < CTP) { W = Wih; row = ct * 16 + c16; }
    else          { W = Wself; row = (ct - CTP) * 16 + c16; }
#pragma unroll
    for (int kb = 0; kb < KB; ++kb) {
      bf16x8 b = ldb8(W + (size_t)row * DIN + kb * 32 + quad * 8);
      a0 = __builtin_amdgcn_mfma_f32_16x16x32_bf16(afr[0][kb], b, a0, 0, 0, 0);
      a1 = __builtin_amdgcn_mfma_f32_16x16x32_bf16(afr[1][kb], b, a1, 0, 0, 0);
    }
    if (ct < CTP) {
      int c = ct * 16 + c16;
      int gg = c / DIN, cc = c % DIN;
      float bias = bih[c] + bhh[c];
#pragma unroll
      for (int r = 0; r < 4; ++r) {
        P[(size_t)(n0 + quad * 4 + r) * (4 * DIN) + cc * 4 + gg] =
            __float2bfloat16(a0[r] + bias);
        P[(size_t)(n0 + 16 + quad * 4 + r) * (4 * DIN) + cc * 4 + gg] =
            __float2bfloat16(a1[r] + bias);
      }
    } else {
      int c = (ct - CTP) * 16 + c16;
      float bias = bvec[c];
#pragma unroll
      for (int r = 0; r < 4; ++r) {
        S[(size_t)(n0 + quad * 4 + r) * DOUT + c] = a0[r] + bias;
        S[(size_t)(n0 + 16 + quad * 4 + r) * DOUT + c] = a1[r] + bias;
      }
    }
  }
}

// LSTM + fused fc. Block = (DIN/16) waves = 16 nodes.
// Wave wv owns cols [wv*16, wv*16+16) of ALL 4 gates; Whh frags pinned in
// VGPRs (4*KB bf16x8). pf gathers double-buffered; t-loop fully unrolled;
// MFMA accumulators initialized with the gate pre-activations.
template <int DIN, int DOUT, bool RELU, typename OutT>
__global__ __launch_bounds__((DIN / 16) * 64)
__attribute__((amdgpu_waves_per_eu(6))) void lstm_fc_kern(
    const __hip_bfloat16* __restrict__ P,   // [N][DIN][4] gate-packed bf16
    const float* __restrict__ S,            // [N, DOUT] f32
    const __hip_bfloat16* __restrict__ Whh, // bf16 [4*DIN, DIN]
    const __hip_bfloat16* __restrict__ Wng, // bf16 [DOUT, DIN]
    const int* __restrict__ nidx,           // [N, 16]
    OutT* __restrict__ outp) {              // [N, DOUT]
  constexpr int W = DIN / 16;    // waves per block
  constexpr int KB = DIN / 32;   // MFMA K blocks
  constexpr int HS = DIN + 8;    // h row stride

  __shared__ __align__(16) __hip_bfloat16 hl[2][16 * HS];
  __shared__ int idxl[16 * KNE];

  const int n0 = blockIdx.x * 16;
  const int tid = threadIdx.x;
  const int wv = tid >> 6;
  const int lane = tid & 63;
  const int quad = lane >> 4;
  const int c16 = lane & 15;
  const int col = wv * 16 + c16;  // this lane's h/gate column

  for (int i = tid; i < 16 * KNE; i += W * 64) idxl[i] = nidx[n0 * KNE + i];
  __syncthreads();  // idxl ready

  uint2 pf[2][4];
  auto loadpf = [&](int t, int b) {
#pragma unroll
    for (int r = 0; r < 4; ++r) {
      int src = idxl[(quad * 4 + r) * KNE + t];
      pf[b][r] =
          reinterpret_cast<const uint2*>(P + (size_t)src * (4 * DIN))[col];
    }
  };

  loadpf(0, 0);  // needed immediately at t=0

  // Persistent Whh B-fragments: rows g*DIN + col. Pinned against remat.
  bf16x8 Bp[4][KB];
#pragma unroll
  for (int g = 0; g < 4; ++g)
#pragma unroll
    for (int kb = 0; kb < KB; ++kb) {
      Bp[g][kb] =
          ldb8(Whh + (size_t)(g * DIN + col) * DIN + kb * 32 + quad * 8);
      pin(Bp[g][kb]);
    }

  loadpf(1, 1);  // prefetch step 1

  float cst[4];
#pragma unroll
  for (int r = 0; r < 4; ++r) cst[r] = 0.f;

  // Accumulator init = gate pre-activations (C=pf instead of C=0 then add).
  auto initag = [&](int b, f32x4 (&ag)[4]) {
#pragma unroll
    for (int r = 0; r < 4; ++r) {
      ag[0][r] = b2f_lo(pf[b][r].x);
      ag[1][r] = b2f_hi(pf[b][r].x);
      ag[2][r] = b2f_lo(pf[b][r].y);
      ag[3][r] = b2f_hi(pf[b][r].y);
    }
  };

  // gates: element (node m = quad*4+r, col); ag already includes pre-acts.
  auto gates = [&](int hb, const f32x4 (&ag)[4]) {
#pragma unroll
    for (int r = 0; r < 4; ++r) {
      float cc = sigf(ag[1][r]) * cst[r] + sigf(ag[0][r]) * tanhf_(ag[2][r]);
      cst[r] = cc;
      hl[hb][(quad * 4 + r) * HS + col] =
          __float2bfloat16(sigf(ag[3][r]) * tanhf_(cc));
    }
  };

  // t = 0: h == 0 -> gates directly from pre-acts.
  {
    f32x4 ag[4];
    initag(0, ag);
    gates(0, ag);
  }

#pragma unroll
  for (int t = 1; t < KNE; ++t) {  // FULL unroll: all pf/hl indices static
    __syncthreads();  // h(t-1) visible
    if (t + 1 < KNE) loadpf(t + 1, (t + 1) & 1);
    const int pb = (t - 1) & 1;
    bf16x8 Af[KB];
#pragma unroll
    for (int kb = 0; kb < KB; ++kb)
      Af[kb] = ldb8(&hl[pb][c16 * HS + kb * 32 + quad * 8]);
    f32x4 ag[4];
    initag(t & 1, ag);
#pragma unroll
    for (int kb = 0; kb < KB; ++kb)
#pragma unroll
      for (int g = 0; g < 4; ++g)
        ag[g] = __builtin_amdgcn_mfma_f32_16x16x32_bf16(Af[kb], Bp[g][kb],
                                                        ag[g], 0, 0, 0);
    gates(t & 1, ag);
  }

  const f32x4 zz = {0.f, 0.f, 0.f, 0.f};
  __syncthreads();  // final h (hl[1], 15&1==1) visible
  bf16x8 Hf[KB];
#pragma unroll
  for (int kb = 0; kb < KB; ++kb)
    Hf[kb] = ldb8(&hl[1][c16 * HS + kb * 32 + quad * 8]);
  for (int ct = wv; ct < DOUT / 16; ct += W) {
    f32x4 a = zz;
#pragma unroll
    for (int kb = 0; kb < KB; ++kb) {
      bf16x8 b = ldb8(Wng + (size_t)(ct * 16 + c16) * DIN + kb * 32 + quad * 8);
      a = __builtin_amdgcn_mfma_f32_16x16x32_bf16(Hf[kb], b, a, 0, 0, 0);
    }
#pragma unroll
    for (int r = 0; r < 4; ++r) {
      int n = n0 + quad * 4 + r;
      int c = ct * 16 + c16;
      float v = a[r] + S[(size_t)n * DOUT + c];
      if (RELU) v = fmaxf(v, 0.f);
      if constexpr (sizeof(OutT) == 2)
        outp[(size_t)n * DOUT + c] = __float2bfloat16(v);
      else
        outp[(size_t)n * DOUT + c] = v;
    }
  }
}

extern "C" void kernel_launch(void* const* d_in, const int* in_sizes, int n_in,
                              void* d_out, int out_size, void* d_ws,
                              size_t ws_size, hipStream_t stream) {
  (void)in_sizes; (void)n_in; (void)out_size; (void)ws_size;
  const float* p = (const float*)d_in[0];
  const int* nidx = (const int*)d_in[1];
  const float* L[3][7];
  for (int l = 0; l < 3; ++l)
    for (int j = 0; j < 7; ++j)
      L[l][j] = (const float*)d_in[2 + 7 * l + j];
  // per-layer params: 0=Wih 1=Whh 2=bih 3=bhh 4=Wself 5=Wneigh 6=b

  char* w = (char*)d_ws;
  __hip_bfloat16* feat0 = (__hip_bfloat16*)(w);             // N*64*2  = 2.56MB
  __hip_bfloat16* feat1 = (__hip_bfloat16*)(w + 2560000);   // N*128*2 = 5.12MB
  __hip_bfloat16* feat2 = (__hip_bfloat16*)(w + 7680000);   // N*128*2 = 5.12MB
  __hip_bfloat16* Pb    = (__hip_bfloat16*)(w + 12800000);  // N*512*2 = 20.48MB
  float*          Sb    = (float*)(w + 33280000);           // N*128*4 = 10.24MB
  __hip_bfloat16* wb    = (__hip_bfloat16*)(w + 43520000);  // bf16 weights

  const int din_[3] = {64, 128, 128}, dout_[3] = {128, 128, 32};
  __hip_bfloat16 *Wih_b[3], *Whh_b[3], *Wself_b[3], *Wng_b[3];
  size_t off = 0;
  for (int l = 0; l < 3; ++l) {
    int din = din_[l], dout = dout_[l];
    Wih_b[l] = wb + off;   off += (size_t)4 * din * din;
    Whh_b[l] = wb + off;   off += (size_t)4 * din * din;
    Wself_b[l] = wb + off; off += (size_t)dout * din;
    Wng_b[l] = wb + off;   off += (size_t)dout * din;
  }
  for (int l = 0; l < 3; ++l) {
    int din = din_[l], dout = dout_[l];
    int n0 = 4 * din * din, n2 = dout * din;
    int tot = 2 * n0 + 2 * n2;
    cvt4<<<(tot + 255) / 256, 256, 0, stream>>>(
        L[l][0], n0, L[l][1], n0, L[l][4], n2, L[l][5], n2,
        Wih_b[l], Whh_b[l], Wself_b[l], Wng_b[l]);
  }

  build_feat0<<<(N_NODES * 64 + 255) / 256, 256, 0, stream>>>(p, feat0);

  // layer 0: din=64, dout=128  (lstm block = 4 waves)
  proj_kern<64, 128><<<N_NODES / 32, 256, 0, stream>>>(
      feat0, Wih_b[0], L[0][2], L[0][3], Wself_b[0], L[0][6], Pb, Sb);
  lstm_fc_kern<64, 128, true, __hip_bfloat16>
      <<<N_NODES / 16, 256, 0, stream>>>(Pb, Sb, Whh_b[0], Wng_b[0], nidx,
                                         feat1);

  // layer 1: din=128, dout=128  (lstm block = 8 waves)
  proj_kern<128, 128><<<N_NODES / 32, 256, 0, stream>>>(
      feat1, Wih_b[1], L[1][2], L[1][3], Wself_b[1], L[1][6], Pb, Sb);
  lstm_fc_kern<128, 128, true, __hip_bfloat16>
      <<<N_NODES / 16, 512, 0, stream>>>(Pb, Sb, Whh_b[1], Wng_b[1], nidx,
                                         feat2);

  // layer 2: din=128, dout=32 (no relu; final fp32 output)
  proj_kern<128, 32><<<N_NODES / 32, 256, 0, stream>>>(
      feat2, Wih_b[2], L[2][2], L[2][3], Wself_b[2], L[2][6], Pb, Sb);
  lstm_fc_kern<128, 32, false, float>
      <<<N_NODES / 16, 512, 0, stream>>>(Pb, Sb, Whh_b[2], Wng_b[2], nidx,
                                         (float*)d_out);
}

// Round 11
// 344.625 us; speedup vs baseline: 2.8161x; 2.1528x over previous
//
#include <hip/hip_runtime.h>
#include <hip/hip_bf16.h>
#include <stdint.h>

// Net_61272003445332: GraphSAGE w/ LSTM aggregator, N=20000, K=16,
// dims: l0 (din=64,dout=128), l1 (128,128), l2 (128,32).
// R10: (a) lstm waves_per_eu reverted to the empirically-safe (4)
//      (R8 (8): VGPR 32, 355MB scratch; R9 (6): VGPR 40, 245MB scratch —
//      the attr squeezes the register budget far below 512/n; only (4)
//      holds the kernel's true 64-VGPR fit). C=pf accumulator-init kept.
//      (b) proj_kern restructured: per column-tile, all 4 gates accumulated
//      in registers, then ONE packed uint2 (i,f,g,o) store per (node,col) —
//      coalesced 8B writes replacing 2B stride-8 scatter stores.

#define N_NODES 20000
#define KNE 16

typedef __bf16 bf16x8 __attribute__((ext_vector_type(8)));
typedef float f32x4 __attribute__((ext_vector_type(4)));

__device__ __forceinline__ bf16x8 ldb8(const __hip_bfloat16* p) {
  uint4 u = *reinterpret_cast<const uint4*>(p);
  return __builtin_bit_cast(bf16x8, u);
}
// Anti-rematerialization pin: per-32-bit-word no-op asm.
__device__ __forceinline__ void pin(bf16x8& v) {
  uint4 u = __builtin_bit_cast(uint4, v);
  asm volatile("" : "+v"(u.x), "+v"(u.y), "+v"(u.z), "+v"(u.w));
  v = __builtin_bit_cast(bf16x8, u);
}
__device__ __forceinline__ float b2f_lo(uint32_t u) {
  return __builtin_bit_cast(float, u << 16);
}
__device__ __forceinline__ float b2f_hi(uint32_t u) {
  return __builtin_bit_cast(float, u & 0xffff0000u);
}
__device__ __forceinline__ uint32_t pk2(float a, float b) {
  uint32_t ua = (uint32_t)__builtin_bit_cast(unsigned short, __float2bfloat16(a));
  uint32_t ub = (uint32_t)__builtin_bit_cast(unsigned short, __float2bfloat16(b));
  return ua | (ub << 16);
}
// NaN-safe, clamp-free saturating forms.
__device__ __forceinline__ float sigf(float x) {
  float t = __builtin_amdgcn_exp2f(-1.442695041f * x);
  return __builtin_amdgcn_rcpf(1.f + t);
}
__device__ __forceinline__ float tanhf_(float x) {
  float t = __builtin_amdgcn_exp2f(2.885390082f * x);
  return 1.f - 2.f * __builtin_amdgcn_rcpf(t + 1.f);
}

__global__ void build_feat0(const float* __restrict__ p,
                            __hip_bfloat16* __restrict__ f0) {
  int i = blockIdx.x * 256 + threadIdx.x;
  if (i >= N_NODES * 64) return;
  int n = i >> 6, c = i & 63;
  float v = (c == 0) ? ((float)KNE / (float)N_NODES) : p[n * 63 + c - 1];
  f0[i] = __float2bfloat16(v);
}

__global__ void cvt4(const float* __restrict__ s0, int n0,
                     const float* __restrict__ s1, int n1,
                     const float* __restrict__ s2, int n2,
                     const float* __restrict__ s3, int n3,
                     __hip_bfloat16* __restrict__ d0,
                     __hip_bfloat16* __restrict__ d1,
                     __hip_bfloat16* __restrict__ d2,
                     __hip_bfloat16* __restrict__ d3) {
  int i = blockIdx.x * 256 + threadIdx.x;
  if (i < n0) { d0[i] = __float2bfloat16(s0[i]); return; }
  i -= n0;
  if (i < n1) { d1[i] = __float2bfloat16(s1[i]); return; }
  i -= n1;
  if (i < n2) { d2[i] = __float2bfloat16(s2[i]); return; }
  i -= n2;
  if (i < n3) d3[i] = __float2bfloat16(s3[i]);
}

// P = feat@Wih.T + (bih+bhh) -> bf16 GATE-PACKED: P[n][cc*4+g] (uint2/col)
// S = feat@Wself.T + b       -> f32 [N,DOUT]
// Column-tile loop: all 4 gates of a column accumulated, then one packed
// 8B store per (node,col) -> fully coalesced P writes.
template <int DIN, int DOUT>
__global__ __launch_bounds__(256, 2) void proj_kern(
    const __hip_bfloat16* __restrict__ feat,
    const __hip_bfloat16* __restrict__ Wih,   // bf16 [4*DIN, DIN]
    const float* __restrict__ bih,
    const float* __restrict__ bhh,
    const __hip_bfloat16* __restrict__ Wself, // bf16 [DOUT, DIN]
    const float* __restrict__ bvec,
    __hip_bfloat16* __restrict__ P, float* __restrict__ S) {
  constexpr int KB = DIN / 32;
  constexpr int CCT = DIN / 16;    // packed-P col tiles
  constexpr int CTS = DOUT / 16;   // S col tiles
  const int n0 = blockIdx.x * 32;
  const int tid = threadIdx.x;
  const int wv = tid >> 6;
  const int lane = tid & 63;
  const int quad = lane >> 4;
  const int c16 = lane & 15;

  bf16x8 afr[2][KB];
#pragma unroll
  for (int rt = 0; rt < 2; ++rt)
#pragma unroll
    for (int kb = 0; kb < KB; ++kb)
      afr[rt][kb] =
          ldb8(feat + (size_t)(n0 + rt * 16 + c16) * DIN + kb * 32 + quad * 8);

  const f32x4 zz = {0.f, 0.f, 0.f, 0.f};
  for (int ct = wv; ct < CCT + CTS; ct += 4) {
    if (ct < CCT) {
      const int cc = ct * 16 + c16;
      f32x4 ag[4][2];
#pragma unroll
      for (int g = 0; g < 4; ++g) { ag[g][0] = zz; ag[g][1] = zz; }
#pragma unroll
      for (int kb = 0; kb < KB; ++kb)
#pragma unroll
        for (int g = 0; g < 4; ++g) {
          bf16x8 b = ldb8(Wih + (size_t)(g * DIN + cc) * DIN + kb * 32 +
                          quad * 8);
          ag[g][0] = __builtin_amdgcn_mfma_f32_16x16x32_bf16(afr[0][kb], b,
                                                             ag[g][0], 0, 0, 0);
          ag[g][1] = __builtin_amdgcn_mfma_f32_16x16x32_bf16(afr[1][kb], b,
                                                             ag[g][1], 0, 0, 0);
        }
      float bi = bih[cc] + bhh[cc];
      float bff = bih[DIN + cc] + bhh[DIN + cc];
      float bg = bih[2 * DIN + cc] + bhh[2 * DIN + cc];
      float bo = bih[3 * DIN + cc] + bhh[3 * DIN + cc];
      uint2* Pp = reinterpret_cast<uint2*>(P);
#pragma unroll
      for (int rt = 0; rt < 2; ++rt)
#pragma unroll
        for (int r = 0; r < 4; ++r) {
          int n = n0 + rt * 16 + quad * 4 + r;
          uint2 u;
          u.x = pk2(ag[0][rt][r] + bi, ag[1][rt][r] + bff);
          u.y = pk2(ag[2][rt][r] + bg, ag[3][rt][r] + bo);
          Pp[(size_t)n * DIN + cc] = u;
        }
    } else {
      const int c = (ct - CCT) * 16 + c16;
      f32x4 a0 = zz, a1 = zz;
#pragma unroll
      for (int kb = 0; kb < KB; ++kb) {
        bf16x8 b = ldb8(Wself + (size_t)c * DIN + kb * 32 + quad * 8);
        a0 = __builtin_amdgcn_mfma_f32_16x16x32_bf16(afr[0][kb], b, a0, 0, 0, 0);
        a1 = __builtin_amdgcn_mfma_f32_16x16x32_bf16(afr[1][kb], b, a1, 0, 0, 0);
      }
      float bias = bvec[c];
#pragma unroll
      for (int r = 0; r < 4; ++r) {
        S[(size_t)(n0 + quad * 4 + r) * DOUT + c] = a0[r] + bias;
        S[(size_t)(n0 + 16 + quad * 4 + r) * DOUT + c] = a1[r] + bias;
      }
    }
  }
}

// LSTM + fused fc. Block = (DIN/16) waves = 16 nodes.
// Wave wv owns cols [wv*16, wv*16+16) of ALL 4 gates; Whh frags pinned in
// VGPRs (4*KB bf16x8). pf gathers double-buffered; t-loop fully unrolled;
// MFMA accumulators initialized with the gate pre-activations.
template <int DIN, int DOUT, bool RELU, typename OutT>
__global__ __launch_bounds__((DIN / 16) * 64)
__attribute__((amdgpu_waves_per_eu(4))) void lstm_fc_kern(
    const __hip_bfloat16* __restrict__ P,   // [N][DIN][4] gate-packed bf16
    const float* __restrict__ S,            // [N, DOUT] f32
    const __hip_bfloat16* __restrict__ Whh, // bf16 [4*DIN, DIN]
    const __hip_bfloat16* __restrict__ Wng, // bf16 [DOUT, DIN]
    const int* __restrict__ nidx,           // [N, 16]
    OutT* __restrict__ outp) {              // [N, DOUT]
  constexpr int W = DIN / 16;    // waves per block
  constexpr int KB = DIN / 32;   // MFMA K blocks
  constexpr int HS = DIN + 8;    // h row stride

  __shared__ __align__(16) __hip_bfloat16 hl[2][16 * HS];
  __shared__ int idxl[16 * KNE];

  const int n0 = blockIdx.x * 16;
  const int tid = threadIdx.x;
  const int wv = tid >> 6;
  const int lane = tid & 63;
  const int quad = lane >> 4;
  const int c16 = lane & 15;
  const int col = wv * 16 + c16;  // this lane's h/gate column

  for (int i = tid; i < 16 * KNE; i += W * 64) idxl[i] = nidx[n0 * KNE + i];
  __syncthreads();  // idxl ready

  uint2 pf[2][4];
  auto loadpf = [&](int t, int b) {
#pragma unroll
    for (int r = 0; r < 4; ++r) {
      int src = idxl[(quad * 4 + r) * KNE + t];
      pf[b][r] =
          reinterpret_cast<const uint2*>(P + (size_t)src * (4 * DIN))[col];
    }
  };

  loadpf(0, 0);  // needed immediately at t=0

  // Persistent Whh B-fragments: rows g*DIN + col. Pinned against remat.
  bf16x8 Bp[4][KB];
#pragma unroll
  for (int g = 0; g < 4; ++g)
#pragma unroll
    for (int kb = 0; kb < KB; ++kb) {
      Bp[g][kb] =
          ldb8(Whh + (size_t)(g * DIN + col) * DIN + kb * 32 + quad * 8);
      pin(Bp[g][kb]);
    }

  loadpf(1, 1);  // prefetch step 1

  float cst[4];
#pragma unroll
  for (int r = 0; r < 4; ++r) cst[r] = 0.f;

  // Accumulator init = gate pre-activations (C=pf instead of C=0 then add).
  auto initag = [&](int b, f32x4 (&ag)[4]) {
#pragma unroll
    for (int r = 0; r < 4; ++r) {
      ag[0][r] = b2f_lo(pf[b][r].x);
      ag[1][r] = b2f_hi(pf[b][r].x);
      ag[2][r] = b2f_lo(pf[b][r].y);
      ag[3][r] = b2f_hi(pf[b][r].y);
    }
  };

  // gates: element (node m = quad*4+r, col); ag already includes pre-acts.
  auto gates = [&](int hb, const f32x4 (&ag)[4]) {
#pragma unroll
    for (int r = 0; r < 4; ++r) {
      float cc = sigf(ag[1][r]) * cst[r] + sigf(ag[0][r]) * tanhf_(ag[2][r]);
      cst[r] = cc;
      hl[hb][(quad * 4 + r) * HS + col] =
          __float2bfloat16(sigf(ag[3][r]) * tanhf_(cc));
    }
  };

  // t = 0: h == 0 -> gates directly from pre-acts.
  {
    f32x4 ag[4];
    initag(0, ag);
    gates(0, ag);
  }

#pragma unroll
  for (int t = 1; t < KNE; ++t) {  // FULL unroll: all pf/hl indices static
    __syncthreads();  // h(t-1) visible
    if (t + 1 < KNE) loadpf(t + 1, (t + 1) & 1);
    const int pb = (t - 1) & 1;
    bf16x8 Af[KB];
#pragma unroll
    for (int kb = 0; kb < KB; ++kb)
      Af[kb] = ldb8(&hl[pb][c16 * HS + kb * 32 + quad * 8]);
    f32x4 ag[4];
    initag(t & 1, ag);
#pragma unroll
    for (int kb = 0; kb < KB; ++kb)
#pragma unroll
      for (int g = 0; g < 4; ++g)
        ag[g] = __builtin_amdgcn_mfma_f32_16x16x32_bf16(Af[kb], Bp[g][kb],
                                                        ag[g], 0, 0, 0);
    gates(t & 1, ag);
  }

  const f32x4 zz = {0.f, 0.f, 0.f, 0.f};
  __syncthreads();  // final h (hl[1], 15&1==1) visible
  bf16x8 Hf[KB];
#pragma unroll
  for (int kb = 0; kb < KB; ++kb)
    Hf[kb] = ldb8(&hl[1][c16 * HS + kb * 32 + quad * 8]);
  for (int ct = wv; ct < DOUT / 16; ct += W) {
    f32x4 a = zz;
#pragma unroll
    for (int kb = 0; kb < KB; ++kb) {
      bf16x8 b = ldb8(Wng + (size_t)(ct * 16 + c16) * DIN + kb * 32 + quad * 8);
      a = __builtin_amdgcn_mfma_f32_16x16x32_bf16(Hf[kb], b, a, 0, 0, 0);
    }
#pragma unroll
    for (int r = 0; r < 4; ++r) {
      int n = n0 + quad * 4 + r;
      int c = ct * 16 + c16;
      float v = a[r] + S[(size_t)n * DOUT + c];
      if (RELU) v = fmaxf(v, 0.f);
      if constexpr (sizeof(OutT) == 2)
        outp[(size_t)n * DOUT + c] = __float2bfloat16(v);
      else
        outp[(size_t)n * DOUT + c] = v;
    }
  }
}

extern "C" void kernel_launch(void* const* d_in, const int* in_sizes, int n_in,
                              void* d_out, int out_size, void* d_ws,
                              size_t ws_size, hipStream_t stream) {
  (void)in_sizes; (void)n_in; (void)out_size; (void)ws_size;
  const float* p = (const float*)d_in[0];
  const int* nidx = (const int*)d_in[1];
  const float* L[3][7];
  for (int l = 0; l < 3; ++l)
    for (int j = 0; j < 7; ++j)
      L[l][j] = (const float*)d_in[2 + 7 * l + j];
  // per-layer params: 0=Wih 1=Whh 2=bih 3=bhh 4=Wself 5=Wneigh 6=b

  char* w = (char*)d_ws;
  __hip_bfloat16* feat0 = (__hip_bfloat16*)(w);             // N*64*2  = 2.56MB
  __hip_bfloat16* feat1 = (__hip_bfloat16*)(w + 2560000);   // N*128*2 = 5.12MB
  __hip_bfloat16* feat2 = (__hip_bfloat16*)(w + 7680000);   // N*128*2 = 5.12MB
  __hip_bfloat16* Pb    = (__hip_bfloat16*)(w + 12800000);  // N*512*2 = 20.48MB
  float*          Sb    = (float*)(w + 33280000);           // N*128*4 = 10.24MB
  __hip_bfloat16* wb    = (__hip_bfloat16*)(w + 43520000);  // bf16 weights

  const int din_[3] = {64, 128, 128}, dout_[3] = {128, 128, 32};
  __hip_bfloat16 *Wih_b[3], *Whh_b[3], *Wself_b[3], *Wng_b[3];
  size_t off = 0;
  for (int l = 0; l < 3; ++l) {
    int din = din_[l], dout = dout_[l];
    Wih_b[l] = wb + off;   off += (size_t)4 * din * din;
    Whh_b[l] = wb + off;   off += (size_t)4 * din * din;
    Wself_b[l] = wb + off; off += (size_t)dout * din;
    Wng_b[l] = wb + off;   off += (size_t)dout * din;
  }
  for (int l = 0; l < 3; ++l) {
    int din = din_[l], dout = dout_[l];
    int n0 = 4 * din * din, n2 = dout * din;
    int tot = 2 * n0 + 2 * n2;
    cvt4<<<(tot + 255) / 256, 256, 0, stream>>>(
        L[l][0], n0, L[l][1], n0, L[l][4], n2, L[l][5], n2,
        Wih_b[l], Whh_b[l], Wself_b[l], Wng_b[l]);
  }

  build_feat0<<<(N_NODES * 64 + 255) / 256, 256, 0, stream>>>(p, feat0);

  // layer 0: din=64, dout=128  (lstm block = 4 waves)
  proj_kern<64, 128><<<N_NODES / 32, 256, 0, stream>>>(
      feat0, Wih_b[0], L[0][2], L[0][3], Wself_b[0], L[0][6], Pb, Sb);
  lstm_fc_kern<64, 128, true, __hip_bfloat16>
      <<<N_NODES / 16, 256, 0, stream>>>(Pb, Sb, Whh_b[0], Wng_b[0], nidx,
                                         feat1);

  // layer 1: din=128, dout=128  (lstm block = 8 waves)
  proj_kern<128, 128><<<N_NODES / 32, 256, 0, stream>>>(
      feat1, Wih_b[1], L[1][2], L[1][3], Wself_b[1], L[1][6], Pb, Sb);
  lstm_fc_kern<128, 128, true, __hip_bfloat16>
      <<<N_NODES / 16, 512, 0, stream>>>(Pb, Sb, Whh_b[1], Wng_b[1], nidx,
                                         feat2);

  // layer 2: din=128, dout=32 (no relu; final fp32 output)
  proj_kern<128, 32><<<N_NODES / 32, 256, 0, stream>>>(
      feat2, Wih_b[2], L[2][2], L[2][3], Wself_b[2], L[2][6], Pb, Sb);
  lstm_fc_kern<128, 32, false, float>
      <<<N_NODES / 16, 512, 0, stream>>>(Pb, Sb, Whh_b[2], Wng_b[2], nidx,
                                         (float*)d_out);
}